// Round 15
// baseline (244.379 us; speedup 1.0000x reference)
//
#include <hip/hip_runtime.h>
#include <math.h>

#define BSZ  16
#define DIM  768
#define SEQA 1024
#define SEQB 1024

typedef float f32x4 __attribute__((ext_vector_type(4)));
typedef long long llong;

__device__ inline void gload_lds16(const void* g, void* l) {
    __builtin_amdgcn_global_load_lds(
        (const __attribute__((address_space(1))) void*)g,
        (__attribute__((address_space(3))) void*)l, 16, 0, 0);
}

// ---- float <-> order-preserving uint key (atomicMax on floats) ----
__device__ inline unsigned enc_key(float f) {
    unsigned u = __float_as_uint(f);
    return (u & 0x80000000u) ? ~u : (u | 0x80000000u);
}
__device__ inline float dec_key(unsigned k) {
    return (k & 0x80000000u) ? __uint_as_float(k ^ 0x80000000u) : __uint_as_float(~k);
}

// ---- fp8 e4m3 (OCP) pack helpers ----
__device__ inline unsigned pk4_fp8(float a, float b, float c, float d) {
    int v = 0;
    v = __builtin_amdgcn_cvt_pk_fp8_f32(a, b, v, false);
    v = __builtin_amdgcn_cvt_pk_fp8_f32(c, d, v, true);
    return (unsigned)v;
}
__device__ inline unsigned char f2fp8(float a) {
    return (unsigned char)(__builtin_amdgcn_cvt_pk_fp8_f32(a, a, 0, false) & 0xFF);
}

// tanh via hardware exp: exact 1.0f in saturation, ~1e-6 error mid-range
__device__ inline float fast_tanh(float x) {
    float ax = fabsf(x);
    float u = __expf(-2.0f * ax);
    float th = __fdividef(1.0f - u, 1.0f + u);
    return copysignf(th, x);
}

// ---- prepass: X[b][DIM][SEQ] f32 -> Xt[b][SEQ][DIM] fp8 for A (z<16) and B (z>=16) ----
__global__ __launch_bounds__(256) void t_cast_AB(const float* __restrict__ A,
                                                 const float* __restrict__ B,
                                                 unsigned char* __restrict__ At,
                                                 unsigned char* __restrict__ Bt) {
    __shared__ float tl[64][68];
    const int z = blockIdx.z;
    const float* X = (z < BSZ) ? A : B;
    unsigned char* Y = (z < BSZ) ? At : Bt;
    const int b = z & 15;
    const int d0 = blockIdx.y * 64;
    const int s0 = blockIdx.x * 64;
    const int tid = threadIdx.x;
    const int rr = tid >> 4, c4 = tid & 15;  // float4 loader coords
    const float* Xb = X + ((size_t)b * DIM + d0) * SEQA + s0;
#pragma unroll
    for (int i = 0; i < 4; i++) {
        int row = i * 16 + rr;
        float4 v = *(const float4*)&Xb[(size_t)row * SEQA + c4 * 4];
        *(float4*)&tl[row][c4 * 4] = v;
    }
    __syncthreads();
    unsigned char* Yb = Y + ((size_t)b * SEQA + s0) * DIM + d0;
    const int m = tid & 15, sl = tid >> 4;
#pragma unroll
    for (int i = 0; i < 4; i++) {
        int s = sl + 16 * i;
        unsigned v = pk4_fp8(tl[4 * m + 0][s], tl[4 * m + 1][s], tl[4 * m + 2][s], tl[4 * m + 3][s]);
        *(unsigned*)&Yb[(size_t)s * DIM + 4 * m] = v;
    }
}

// ---- prepass: U[d][e] f32 -> Ut[e][d] fp8 ; also init max-keys ----
__global__ __launch_bounds__(256) void t_cast_U(const float* __restrict__ U,
                                                unsigned char* __restrict__ Ut,
                                                unsigned* __restrict__ keyA,
                                                unsigned* __restrict__ keyB) {
    __shared__ float tl[64][68];
    const int d0 = blockIdx.y * 64;
    const int e0 = blockIdx.x * 64;
    const int tid = threadIdx.x;
    const int bid = blockIdx.y * gridDim.x + blockIdx.x;
    if (bid < 64) {
        int i = bid * 256 + tid;
        keyA[i] = 0u;
        keyB[i] = 0u;
    }
    const int rr = tid >> 4, c4 = tid & 15;
#pragma unroll
    for (int i = 0; i < 4; i++) {
        int row = i * 16 + rr;
        float4 v = *(const float4*)&U[(size_t)(d0 + row) * DIM + e0 + c4 * 4];
        *(float4*)&tl[row][c4 * 4] = v;
    }
    __syncthreads();
    const int m = tid & 15, sl = tid >> 4;
#pragma unroll
    for (int i = 0; i < 4; i++) {
        int e = sl + 16 * i;
        unsigned v = pk4_fp8(tl[4 * m + 0][e], tl[4 * m + 1][e], tl[4 * m + 2][e], tl[4 * m + 3][e]);
        *(unsigned*)&Ut[(size_t)(e0 + e) * DIM + d0 + 4 * m] = v;
    }
}

// Stage a 128-row x 128-byte tile into LDS with granule-XOR swizzle (4-wave form).
// Wave `wid` covers rows [wid*32, wid*32+32). 4 gloads/wave.
__device__ inline void stage_tile(const unsigned char* __restrict__ src, int row0,
                                  int kbyte0, unsigned char* lds, int wid, int lane) {
    const int r8 = lane >> 3;              // row within 8-row group
    const int g  = lane & 7;               // dest granule slot
    const int gg = g ^ (r8 & 7);           // source granule (XOR swizzle)
#pragma unroll
    for (int t = 0; t < 4; ++t) {
        int row = row0 + wid * 32 + t * 8 + r8;
        gload_lds16(src + (size_t)row * DIM + kbyte0 + gg * 16,
                    lds + (wid * 32 + t * 8) * 128 + lane * 16);
    }
}

// Stage a 64-row x 128-byte tile (4 waves, wave wid covers rows [wid*16,+16)).
// Same row pitch (128B) and granule-XOR as stage_tile -> frag_read unchanged.
__device__ inline void stage64(const unsigned char* __restrict__ src, int kbyte0,
                               unsigned char* lds, int wid, int lane) {
    const int r8 = lane >> 3;
    const int g  = lane & 7;
    const int gg = g ^ (r8 & 7);
#pragma unroll
    for (int t = 0; t < 2; ++t) {
        int row = wid * 16 + t * 8 + r8;
        gload_lds16(src + (size_t)row * DIM + kbyte0 + gg * 16,
                    lds + (wid * 16 + t * 8) * 128 + lane * 16);
    }
}

// Read an 8-byte fp8 fragment (16 rows x k-slice) with matching XOR un-swizzle.
// rowbase multiple of 16; h = 32-byte k-slice index (0..3).
__device__ inline llong frag_read(const unsigned char* lds, int rowbase, int l15,
                                  int quad, int h) {
    int gg = 2 * h + (quad >> 1);
    int off = (rowbase + l15) * 128 + ((gg ^ (l15 & 7)) << 4) + (quad & 1) * 8;
    return *(const llong*)(lds + off);
}

// ---- k1: Ct[b][s][e] = sum_d At[b][s][d] * Ut[e][d]  (fp8 MFMA, 128x128, BK=128) ----
// R5-measured structure: 768 blocks = 3/CU balanced at 3-resident.
__global__ __launch_bounds__(256, 3) void k1_ua(const unsigned char* __restrict__ At,
                                                const unsigned char* __restrict__ Ut,
                                                unsigned char* __restrict__ Ct) {
    __shared__ __align__(16) unsigned char As[128 * 128];
    __shared__ __align__(16) unsigned char Us[128 * 128];
    const int b  = blockIdx.z;
    const int s0 = blockIdx.x * 128;
    const int e0 = blockIdx.y * 128;
    const int tid = threadIdx.x;
    const int lane = tid & 63;
    const int wid = tid >> 6;
    const int wr = wid >> 1, wc = wid & 1;
    const int quad = lane >> 4, l15 = lane & 15;

    const unsigned char* Atb = At + (size_t)b * SEQA * DIM;
    f32x4 acc[4][4] = {};

    for (int d0 = 0; d0 < DIM; d0 += 128) {
        stage_tile(Atb + (size_t)s0 * DIM, 0, d0, As, wid, lane);
        stage_tile(Ut + (size_t)e0 * DIM, 0, d0, Us, wid, lane);
        __syncthreads();
#pragma unroll
        for (int h = 0; h < 4; ++h) {
            llong av[4], bv[4];
#pragma unroll
            for (int i = 0; i < 4; ++i) av[i] = frag_read(As, wr * 64 + 16 * i, l15, quad, h);
#pragma unroll
            for (int j = 0; j < 4; ++j) bv[j] = frag_read(Us, wc * 64 + 16 * j, l15, quad, h);
#pragma unroll
            for (int i = 0; i < 4; ++i)
#pragma unroll
                for (int j = 0; j < 4; ++j)
                    acc[i][j] = __builtin_amdgcn_mfma_f32_16x16x32_fp8_fp8(av[i], bv[j], acc[i][j], 0, 0, 0);
        }
        __syncthreads();
    }
    // D: M(s) = wr*64+16i+quad*4+r, N(e) = wc*64+16j+l15 -> byte stores, 16B segments
    unsigned char* Cb = Ct + (size_t)b * SEQA * DIM;
#pragma unroll
    for (int i = 0; i < 4; ++i)
#pragma unroll
        for (int j = 0; j < 4; ++j) {
            int e_g = e0 + wc * 64 + 16 * j + l15;
#pragma unroll
            for (int r = 0; r < 4; ++r) {
                int s_g = s0 + wr * 64 + 16 * i + quad * 4 + r;
                Cb[(size_t)s_g * DIM + e_g] = f2fp8(acc[i][j][r]);
            }
        }
}

// ---- k2: align^T tile = max-then-tanh(Bt x Ct + msk); fused max -> atomic keys ----
// 128(t) x 64(s) tile, acc[4][2]=32 AGPR: frees 32 VGPRs for an 8x float4 mask
// prefetch issued at kernel START (completes under the first K-iteration), so the
// 64 MB mask read overlaps the K-loop instead of being a cold serial tail.
// tanh-after-max: msk in {0,-inf} (documented domain) + tanh monotone =>
// key = (m==-inf) ? m : tanh(m) with m = max(a+msk) is EXACT, and cuts
// 64 fast_tanh/thread to <=18. Grid 2048 = 2 balanced rounds of 4/CU.
__global__ __launch_bounds__(256, 4) void k2_align(const unsigned char* __restrict__ Ct,
                                                   const unsigned char* __restrict__ Bt,
                                                   const float* __restrict__ msk,
                                                   unsigned* __restrict__ keyA,
                                                   unsigned* __restrict__ keyB) {
    __shared__ __align__(16) unsigned char Bs[128 * 128];
    __shared__ __align__(16) unsigned char Cs[64 * 128];
    const int b  = blockIdx.z;
    const int t0 = blockIdx.x * 128;
    const int s0 = blockIdx.y * 64;
    const int tid = threadIdx.x;
    const int lane = tid & 63;
    const int wid = tid >> 6;
    const int wr = wid >> 1, wc = wid & 1;   // wave tile: 64t x 32s
    const int quad = lane >> 4, l15 = lane & 15;

    const unsigned char* Btb = Bt + ((size_t)b * SEQB + t0) * DIM;
    const unsigned char* Ctb = Ct + ((size_t)b * SEQA + s0) * DIM;

    // mask prefetch (8 float4 = 32 VGPR), issued before any staging
    const float* Mb = msk + (size_t)b * SEQA * SEQB;
    float4 mv[4][2];
#pragma unroll
    for (int i = 0; i < 4; ++i)
#pragma unroll
        for (int j = 0; j < 2; ++j) {
            int s_g = s0 + wc * 32 + 16 * j + l15;
            int t_g = t0 + wr * 64 + 16 * i + quad * 4;
            mv[i][j] = *(const float4*)&Mb[(size_t)s_g * SEQB + t_g];
        }

    f32x4 acc[4][2] = {};

    for (int e0 = 0; e0 < DIM; e0 += 128) {
        stage_tile(Btb, 0, e0, Bs, wid, lane);
        stage64(Ctb, e0, Cs, wid, lane);
        __syncthreads();
#pragma unroll
        for (int h = 0; h < 4; ++h) {
            llong av[4], bv[2];
#pragma unroll
            for (int i = 0; i < 4; ++i) av[i] = frag_read(Bs, wr * 64 + 16 * i, l15, quad, h);
#pragma unroll
            for (int j = 0; j < 2; ++j) bv[j] = frag_read(Cs, wc * 32 + 16 * j, l15, quad, h);
#pragma unroll
            for (int i = 0; i < 4; ++i)
#pragma unroll
                for (int j = 0; j < 2; ++j)
                    acc[i][j] = __builtin_amdgcn_mfma_f32_16x16x32_fp8_fp8(av[i], bv[j], acc[i][j], 0, 0, 0);
        }
        __syncthreads();
    }

    // epilogue: add prefetched mask (no tanh yet)
#pragma unroll
    for (int i = 0; i < 4; ++i)
#pragma unroll
        for (int j = 0; j < 2; ++j) {
            acc[i][j][0] += mv[i][j].x;
            acc[i][j][1] += mv[i][j].y;
            acc[i][j][2] += mv[i][j].z;
            acc[i][j][3] += mv[i][j].w;
        }
    // keyA[s]: max over t (in-lane i,r; cross-quad), tanh once at the end
#pragma unroll
    for (int j = 0; j < 2; ++j) {
        float m = -INFINITY;
#pragma unroll
        for (int i = 0; i < 4; ++i)
#pragma unroll
            for (int r = 0; r < 4; ++r) m = fmaxf(m, acc[i][j][r]);
        m = fmaxf(m, __shfl_xor(m, 16));
        m = fmaxf(m, __shfl_xor(m, 32));
        if (quad == 0) {
            float kv = (m == -INFINITY) ? m : fast_tanh(m);
            atomicMax(&keyA[b * SEQA + s0 + wc * 32 + 16 * j + l15], enc_key(kv));
        }
    }
    // keyB[t]: max over s (in-lane j; cross-l15), tanh once at the end
#pragma unroll
    for (int i = 0; i < 4; ++i)
#pragma unroll
        for (int r = 0; r < 4; ++r) {
            float m = fmaxf(acc[i][0][r], acc[i][1][r]);
            m = fmaxf(m, __shfl_xor(m, 1));
            m = fmaxf(m, __shfl_xor(m, 2));
            m = fmaxf(m, __shfl_xor(m, 4));
            m = fmaxf(m, __shfl_xor(m, 8));
            if (l15 == 0) {
                float kv = (m == -INFINITY) ? m : fast_tanh(m);
                atomicMax(&keyB[b * SEQB + t0 + wr * 64 + 16 * i + quad * 4 + r], enc_key(kv));
            }
        }
}

// ---- k3: softmax over per-token maxes ----
__global__ __launch_bounds__(256) void k3_softmax(const unsigned* __restrict__ keyA,
                                                  const unsigned* __restrict__ keyB,
                                                  float* __restrict__ scoreA,
                                                  float* __restrict__ scoreB) {
    const int b = blockIdx.x;
    const bool isA = (blockIdx.y == 0);
    const unsigned* keys = isA ? (keyA + b * SEQA) : (keyB + b * SEQB);
    float* score = isA ? (scoreA + b * SEQA) : (scoreB + b * SEQB);
    __shared__ float sh[4];
    const int tid = threadIdx.x;
    float m[4];
    float mx = -INFINITY;
#pragma unroll
    for (int k = 0; k < 4; k++) {
        m[k] = dec_key(keys[tid + 256 * k]);
        mx = fmaxf(mx, m[k]);
    }
#pragma unroll
    for (int o = 32; o > 0; o >>= 1) mx = fmaxf(mx, __shfl_down(mx, o, 64));
    if ((tid & 63) == 0) sh[tid >> 6] = mx;
    __syncthreads();
    mx = fmaxf(fmaxf(sh[0], sh[1]), fmaxf(sh[2], sh[3]));
    __syncthreads();
    float e[4];
    float sum = 0.f;
#pragma unroll
    for (int k = 0; k < 4; k++) { e[k] = expf(m[k] - mx); sum += e[k]; }
#pragma unroll
    for (int o = 32; o > 0; o >>= 1) sum += __shfl_down(sum, o, 64);
    if ((tid & 63) == 0) sh[tid >> 6] = sum;
    __syncthreads();
    sum = sh[0] + sh[1] + sh[2] + sh[3];
    float inv = 1.0f / sum;
#pragma unroll
    for (int k = 0; k < 4; k++) score[tid + 256 * k] = e[k] * inv;
}

// ---- k4: out[b,d] = sum_s X[b,d,s] * score[b,s]  (fp32, one wave per row) ----
__global__ __launch_bounds__(256) void k4_out(const float* __restrict__ A,
                                              const float* __restrict__ B,
                                              const float* __restrict__ scoreA,
                                              const float* __restrict__ scoreB,
                                              float* __restrict__ out) {
    const int which = blockIdx.y;
    const int row = blockIdx.x * 4 + (threadIdx.x >> 6);
    const int lane = threadIdx.x & 63;
    const float* X = which ? B : A;
    const float* S = which ? scoreB : scoreA;
    const int b = row / DIM;
    const float4* xr = (const float4*)(X + (size_t)row * SEQA);
    const float4* sr = (const float4*)(S + (size_t)b * SEQA);
    float acc = 0.f;
#pragma unroll
    for (int q = lane; q < SEQA / 4; q += 64) {
        float4 x = xr[q];
        float4 s = sr[q];
        acc += x.x * s.x + x.y * s.y + x.z * s.z + x.w * s.w;
    }
#pragma unroll
    for (int o = 32; o > 0; o >>= 1) acc += __shfl_down(acc, o, 64);
    if (lane == 0) out[which * (BSZ * DIM) + row] = acc;
}

extern "C" void kernel_launch(void* const* d_in, const int* in_sizes, int n_in,
                              void* d_out, int out_size, void* d_ws, size_t ws_size,
                              hipStream_t stream) {
    const float* A   = (const float*)d_in[0];  // (16,768,1024)
    const float* B   = (const float*)d_in[1];  // (16,768,1024)
    const float* msk = (const float*)d_in[2];  // (16,1024,1024)
    const float* U   = (const float*)d_in[3];  // (768,768)
    float* out = (float*)d_out;

    char* ws = (char*)d_ws;
    unsigned char* At = (unsigned char*)ws;                   // 12,582,912
    unsigned char* Bt = (unsigned char*)(ws + 12582912);      // 12,582,912
    unsigned char* Ct = (unsigned char*)(ws + 25165824);      // 12,582,912
    unsigned char* Ut = (unsigned char*)(ws + 37748736);      //    589,824
    unsigned* keyA   = (unsigned*)(ws + 38338560);
    unsigned* keyB   = (unsigned*)(ws + 38404096);
    float*    scoreA = (float*)   (ws + 38469632);
    float*    scoreB = (float*)   (ws + 38535168);

    t_cast_U<<<dim3(DIM / 64, DIM / 64, 1), 256, 0, stream>>>(U, Ut, keyA, keyB);
    t_cast_AB<<<dim3(SEQA / 64, DIM / 64, 2 * BSZ), 256, 0, stream>>>(A, B, At, Bt);
    // k1: R5-measured 128^2 / 3-per-CU structure
    k1_ua<<<dim3(SEQA / 128, DIM / 128, BSZ), 256, 0, stream>>>(At, Ut, Ct);
    // k2: 128(t) x 64(s) tile, mask prefetched in regs, 2048 blocks = 2 rounds of 4/CU
    k2_align<<<dim3(SEQB / 128, SEQA / 64, BSZ), 256, 0, stream>>>(Ct, Bt, msk, keyA, keyB);
    k3_softmax<<<dim3(BSZ, 2), 256, 0, stream>>>(keyA, keyB, scoreA, scoreB);
    k4_out<<<dim3(BSZ * DIM / 4, 2), 256, 0, stream>>>(A, B, scoreA, scoreB, out);
}

// Round 18
// 238.950 us; speedup vs baseline: 1.0227x; 1.0227x over previous
//
#include <hip/hip_runtime.h>
#include <math.h>

#define BSZ  16
#define DIM  768
#define SEQA 1024
#define SEQB 1024

typedef float f32x4 __attribute__((ext_vector_type(4)));
typedef long long llong;

__device__ inline void gload_lds16(const void* g, void* l) {
    __builtin_amdgcn_global_load_lds(
        (const __attribute__((address_space(1))) void*)g,
        (__attribute__((address_space(3))) void*)l, 16, 0, 0);
}

// ---- float <-> order-preserving uint key (atomicMax on floats) ----
__device__ inline unsigned enc_key(float f) {
    unsigned u = __float_as_uint(f);
    return (u & 0x80000000u) ? ~u : (u | 0x80000000u);
}
__device__ inline float dec_key(unsigned k) {
    return (k & 0x80000000u) ? __uint_as_float(k ^ 0x80000000u) : __uint_as_float(~k);
}

// ---- fp8 e4m3 (OCP) pack helpers ----
__device__ inline unsigned pk4_fp8(float a, float b, float c, float d) {
    int v = 0;
    v = __builtin_amdgcn_cvt_pk_fp8_f32(a, b, v, false);
    v = __builtin_amdgcn_cvt_pk_fp8_f32(c, d, v, true);
    return (unsigned)v;
}
__device__ inline unsigned char f2fp8(float a) {
    return (unsigned char)(__builtin_amdgcn_cvt_pk_fp8_f32(a, a, 0, false) & 0xFF);
}

// tanh via hardware exp: exact 1.0f in saturation, ~1e-6 error mid-range
__device__ inline float fast_tanh(float x) {
    float ax = fabsf(x);
    float u = __expf(-2.0f * ax);
    float th = __fdividef(1.0f - u, 1.0f + u);
    return copysignf(th, x);
}

// ---- prepass: X[b][DIM][SEQ] f32 -> Xt[b][SEQ][DIM] fp8 for A (z<16) and B (z>=16) ----
// LDS tile stored TRANSPOSED (tl[s][d], pitch 65 floats): loader writes and packer
// reads are both exactly 2-way bank-aliased (free, m136). The old tl[d][s] pitch-68
// layout made the packer's 4-rows-at-one-column reads an 8-way conflict.
__global__ __launch_bounds__(256) void t_cast_AB(const float* __restrict__ A,
                                                 const float* __restrict__ B,
                                                 unsigned char* __restrict__ At,
                                                 unsigned char* __restrict__ Bt) {
    __shared__ float tl[64 * 65];
    const int z = blockIdx.z;
    const float* X = (z < BSZ) ? A : B;
    unsigned char* Y = (z < BSZ) ? At : Bt;
    const int b = z & 15;
    const int d0 = blockIdx.y * 64;
    const int s0 = blockIdx.x * 64;
    const int tid = threadIdx.x;
    const int rr = tid >> 4, c4 = tid & 15;  // float4 loader coords
    const float* Xb = X + ((size_t)b * DIM + d0) * SEQA + s0;
#pragma unroll
    for (int i = 0; i < 4; i++) {
        int d = i * 16 + rr;
        float4 v = *(const float4*)&Xb[(size_t)d * SEQA + c4 * 4];
        tl[(c4 * 4 + 0) * 65 + d] = v.x;
        tl[(c4 * 4 + 1) * 65 + d] = v.y;
        tl[(c4 * 4 + 2) * 65 + d] = v.z;
        tl[(c4 * 4 + 3) * 65 + d] = v.w;
    }
    __syncthreads();
    unsigned char* Yb = Y + ((size_t)b * SEQA + s0) * DIM + d0;
    const int m = tid & 15, sl = tid >> 4;
#pragma unroll
    for (int i = 0; i < 4; i++) {
        int s = sl + 16 * i;
        unsigned v = pk4_fp8(tl[s * 65 + 4 * m + 0], tl[s * 65 + 4 * m + 1],
                             tl[s * 65 + 4 * m + 2], tl[s * 65 + 4 * m + 3]);
        *(unsigned*)&Yb[(size_t)s * DIM + 4 * m] = v;
    }
}

// ---- prepass: U[d][e] f32 -> Ut[e][d] fp8 ; also init max-keys ----
__global__ __launch_bounds__(256) void t_cast_U(const float* __restrict__ U,
                                                unsigned char* __restrict__ Ut,
                                                unsigned* __restrict__ keyA,
                                                unsigned* __restrict__ keyB) {
    __shared__ float tl[64][68];
    const int d0 = blockIdx.y * 64;
    const int e0 = blockIdx.x * 64;
    const int tid = threadIdx.x;
    const int bid = blockIdx.y * gridDim.x + blockIdx.x;
    if (bid < 64) {
        int i = bid * 256 + tid;
        keyA[i] = 0u;
        keyB[i] = 0u;
    }
    const int rr = tid >> 4, c4 = tid & 15;
#pragma unroll
    for (int i = 0; i < 4; i++) {
        int row = i * 16 + rr;
        float4 v = *(const float4*)&U[(size_t)(d0 + row) * DIM + e0 + c4 * 4];
        *(float4*)&tl[row][c4 * 4] = v;
    }
    __syncthreads();
    const int m = tid & 15, sl = tid >> 4;
#pragma unroll
    for (int i = 0; i < 4; i++) {
        int e = sl + 16 * i;
        unsigned v = pk4_fp8(tl[4 * m + 0][e], tl[4 * m + 1][e], tl[4 * m + 2][e], tl[4 * m + 3][e]);
        *(unsigned*)&Ut[(size_t)(e0 + e) * DIM + d0 + 4 * m] = v;
    }
}

// Stage a 128-row x 128-byte tile into LDS with granule-XOR swizzle (4-wave form).
// Wave `wid` covers rows [wid*32, wid*32+32). 4 gloads/wave.
__device__ inline void stage_tile(const unsigned char* __restrict__ src, int row0,
                                  int kbyte0, unsigned char* lds, int wid, int lane) {
    const int r8 = lane >> 3;              // row within 8-row group
    const int g  = lane & 7;               // dest granule slot
    const int gg = g ^ (r8 & 7);           // source granule (XOR swizzle)
#pragma unroll
    for (int t = 0; t < 4; ++t) {
        int row = row0 + wid * 32 + t * 8 + r8;
        gload_lds16(src + (size_t)row * DIM + kbyte0 + gg * 16,
                    lds + (wid * 32 + t * 8) * 128 + lane * 16);
    }
}

// Read an 8-byte fp8 fragment (16 rows x k-slice) with matching XOR un-swizzle.
// rowbase multiple of 16; h = 32-byte k-slice index (0..3).
__device__ inline llong frag_read(const unsigned char* lds, int rowbase, int l15,
                                  int quad, int h) {
    int gg = 2 * h + (quad >> 1);
    int off = (rowbase + l15) * 128 + ((gg ^ (l15 & 7)) << 4) + (quad & 1) * 8;
    return *(const llong*)(lds + off);
}

// ---- k1: Ct[b][s][e] = sum_d At[b][s][d] * Ut[e][d]  (fp8 MFMA, 128x128, BK=128) ----
// R5-measured structure: 768 blocks = 3/CU balanced at 3-resident.
__global__ __launch_bounds__(256, 3) void k1_ua(const unsigned char* __restrict__ At,
                                                const unsigned char* __restrict__ Ut,
                                                unsigned char* __restrict__ Ct) {
    __shared__ __align__(16) unsigned char As[128 * 128];
    __shared__ __align__(16) unsigned char Us[128 * 128];
    const int b  = blockIdx.z;
    const int s0 = blockIdx.x * 128;
    const int e0 = blockIdx.y * 128;
    const int tid = threadIdx.x;
    const int lane = tid & 63;
    const int wid = tid >> 6;
    const int wr = wid >> 1, wc = wid & 1;
    const int quad = lane >> 4, l15 = lane & 15;

    const unsigned char* Atb = At + (size_t)b * SEQA * DIM;
    f32x4 acc[4][4] = {};

    for (int d0 = 0; d0 < DIM; d0 += 128) {
        stage_tile(Atb + (size_t)s0 * DIM, 0, d0, As, wid, lane);
        stage_tile(Ut + (size_t)e0 * DIM, 0, d0, Us, wid, lane);
        __syncthreads();
#pragma unroll
        for (int h = 0; h < 4; ++h) {
            llong av[4], bv[4];
#pragma unroll
            for (int i = 0; i < 4; ++i) av[i] = frag_read(As, wr * 64 + 16 * i, l15, quad, h);
#pragma unroll
            for (int j = 0; j < 4; ++j) bv[j] = frag_read(Us, wc * 64 + 16 * j, l15, quad, h);
#pragma unroll
            for (int i = 0; i < 4; ++i)
#pragma unroll
                for (int j = 0; j < 4; ++j)
                    acc[i][j] = __builtin_amdgcn_mfma_f32_16x16x32_fp8_fp8(av[i], bv[j], acc[i][j], 0, 0, 0);
        }
        __syncthreads();
    }
    // D: M(s) = wr*64+16i+quad*4+r, N(e) = wc*64+16j+l15 -> byte stores, 16B segments
    unsigned char* Cb = Ct + (size_t)b * SEQA * DIM;
#pragma unroll
    for (int i = 0; i < 4; ++i)
#pragma unroll
        for (int j = 0; j < 4; ++j) {
            int e_g = e0 + wc * 64 + 16 * j + l15;
#pragma unroll
            for (int r = 0; r < 4; ++r) {
                int s_g = s0 + wr * 64 + 16 * i + quad * 4 + r;
                Cb[(size_t)s_g * DIM + e_g] = f2fp8(acc[i][j][r]);
            }
        }
}

// ---- k2: align^T tile = max-then-tanh(Bt x Ct + msk); fused max -> atomic keys ----
// EXACT R5-measured geometry (128x128 tile, (256,4), epilogue per-(i,j) mask load,
// VGPR 64) -- the measured best (47.5us); R10/R15 smaller-tile variants both
// regressed ~15% (staging intensity). Only delta vs R5: tanh moved AFTER the max
// (exact: msk in {0,-inf}, tanh monotone, -inf guarded) -> <=18 tanh/thread vs 64.
__global__ __launch_bounds__(256, 4) void k2_align(const unsigned char* __restrict__ Ct,
                                                   const unsigned char* __restrict__ Bt,
                                                   const float* __restrict__ msk,
                                                   unsigned* __restrict__ keyA,
                                                   unsigned* __restrict__ keyB) {
    __shared__ __align__(16) unsigned char Cs[128 * 128];
    __shared__ __align__(16) unsigned char Bs[128 * 128];
    const int b  = blockIdx.z;
    const int t0 = blockIdx.x * 128;
    const int s0 = blockIdx.y * 128;
    const int tid = threadIdx.x;
    const int lane = tid & 63;
    const int wid = tid >> 6;
    const int wr = wid >> 1, wc = wid & 1;
    const int quad = lane >> 4, l15 = lane & 15;

    f32x4 acc[4][4] = {};

    for (int e0 = 0; e0 < DIM; e0 += 128) {
        stage_tile(Ct + (size_t)(b * SEQA + s0) * DIM, 0, e0, Cs, wid, lane);
        stage_tile(Bt + (size_t)(b * SEQB + t0) * DIM, 0, e0, Bs, wid, lane);
        __syncthreads();
#pragma unroll
        for (int h = 0; h < 4; ++h) {
            llong av[4], bv[4];
#pragma unroll
            for (int i = 0; i < 4; ++i) av[i] = frag_read(Bs, wr * 64 + 16 * i, l15, quad, h);
#pragma unroll
            for (int j = 0; j < 4; ++j) bv[j] = frag_read(Cs, wc * 64 + 16 * j, l15, quad, h);
#pragma unroll
            for (int i = 0; i < 4; ++i)
#pragma unroll
                for (int j = 0; j < 4; ++j)
                    acc[i][j] = __builtin_amdgcn_mfma_f32_16x16x32_fp8_fp8(av[i], bv[j], acc[i][j], 0, 0, 0);
        }
        __syncthreads();
    }

    // epilogue: add mask only (one float4 per (i,j), in place); tanh deferred to keys
    const float* Mb = msk + (size_t)b * SEQA * SEQB;
#pragma unroll
    for (int j = 0; j < 4; ++j) {
        int s_g = s0 + wc * 64 + 16 * j + l15;
#pragma unroll
        for (int i = 0; i < 4; ++i) {
            int t_g = t0 + wr * 64 + 16 * i + quad * 4;
            float4 mvv = *(const float4*)&Mb[(size_t)s_g * SEQB + t_g];
            acc[i][j][0] += mvv.x;
            acc[i][j][1] += mvv.y;
            acc[i][j][2] += mvv.z;
            acc[i][j][3] += mvv.w;
        }
    }
    // keyA[s]: max over t (in-lane i,r; cross-quad), tanh once at the end
#pragma unroll
    for (int j = 0; j < 4; ++j) {
        float m = -INFINITY;
#pragma unroll
        for (int i = 0; i < 4; ++i)
#pragma unroll
            for (int r = 0; r < 4; ++r) m = fmaxf(m, acc[i][j][r]);
        m = fmaxf(m, __shfl_xor(m, 16));
        m = fmaxf(m, __shfl_xor(m, 32));
        if (quad == 0) {
            float kv = (m == -INFINITY) ? m : fast_tanh(m);
            atomicMax(&keyA[b * SEQA + s0 + wc * 64 + 16 * j + l15], enc_key(kv));
        }
    }
    // keyB[t]: max over s (in-lane j; cross-l15), tanh once at the end
#pragma unroll
    for (int i = 0; i < 4; ++i)
#pragma unroll
        for (int r = 0; r < 4; ++r) {
            float m = fmaxf(fmaxf(acc[i][0][r], acc[i][1][r]), fmaxf(acc[i][2][r], acc[i][3][r]));
            m = fmaxf(m, __shfl_xor(m, 1));
            m = fmaxf(m, __shfl_xor(m, 2));
            m = fmaxf(m, __shfl_xor(m, 4));
            m = fmaxf(m, __shfl_xor(m, 8));
            if (l15 == 0) {
                float kv = (m == -INFINITY) ? m : fast_tanh(m);
                atomicMax(&keyB[b * SEQB + t0 + wr * 64 + 16 * i + quad * 4 + r], enc_key(kv));
            }
        }
}

// ---- k3: softmax over per-token maxes ----
__global__ __launch_bounds__(256) void k3_softmax(const unsigned* __restrict__ keyA,
                                                  const unsigned* __restrict__ keyB,
                                                  float* __restrict__ scoreA,
                                                  float* __restrict__ scoreB) {
    const int b = blockIdx.x;
    const bool isA = (blockIdx.y == 0);
    const unsigned* keys = isA ? (keyA + b * SEQA) : (keyB + b * SEQB);
    float* score = isA ? (scoreA + b * SEQA) : (scoreB + b * SEQB);
    __shared__ float sh[4];
    const int tid = threadIdx.x;
    float m[4];
    float mx = -INFINITY;
#pragma unroll
    for (int k = 0; k < 4; k++) {
        m[k] = dec_key(keys[tid + 256 * k]);
        mx = fmaxf(mx, m[k]);
    }
#pragma unroll
    for (int o = 32; o > 0; o >>= 1) mx = fmaxf(mx, __shfl_down(mx, o, 64));
    if ((tid & 63) == 0) sh[tid >> 6] = mx;
    __syncthreads();
    mx = fmaxf(fmaxf(sh[0], sh[1]), fmaxf(sh[2], sh[3]));
    __syncthreads();
    float e[4];
    float sum = 0.f;
#pragma unroll
    for (int k = 0; k < 4; k++) { e[k] = expf(m[k] - mx); sum += e[k]; }
#pragma unroll
    for (int o = 32; o > 0; o >>= 1) sum += __shfl_down(sum, o, 64);
    if ((tid & 63) == 0) sh[tid >> 6] = sum;
    __syncthreads();
    sum = sh[0] + sh[1] + sh[2] + sh[3];
    float inv = 1.0f / sum;
#pragma unroll
    for (int k = 0; k < 4; k++) score[tid + 256 * k] = e[k] * inv;
}

// ---- k4: out[b,d] = sum_s X[b,d,s] * score[b,s]  (fp32, one wave per row) ----
__global__ __launch_bounds__(256) void k4_out(const float* __restrict__ A,
                                              const float* __restrict__ B,
                                              const float* __restrict__ scoreA,
                                              const float* __restrict__ scoreB,
                                              float* __restrict__ out) {
    const int which = blockIdx.y;
    const int row = blockIdx.x * 4 + (threadIdx.x >> 6);
    const int lane = threadIdx.x & 63;
    const float* X = which ? B : A;
    const float* S = which ? scoreB : scoreA;
    const int b = row / DIM;
    const float4* xr = (const float4*)(X + (size_t)row * SEQA);
    const float4* sr = (const float4*)(S + (size_t)b * SEQA);
    float acc = 0.f;
#pragma unroll
    for (int q = lane; q < SEQA / 4; q += 64) {
        float4 x = xr[q];
        float4 s = sr[q];
        acc += x.x * s.x + x.y * s.y + x.z * s.z + x.w * s.w;
    }
#pragma unroll
    for (int o = 32; o > 0; o >>= 1) acc += __shfl_down(acc, o, 64);
    if (lane == 0) out[which * (BSZ * DIM) + row] = acc;
}

extern "C" void kernel_launch(void* const* d_in, const int* in_sizes, int n_in,
                              void* d_out, int out_size, void* d_ws, size_t ws_size,
                              hipStream_t stream) {
    const float* A   = (const float*)d_in[0];  // (16,768,1024)
    const float* B   = (const float*)d_in[1];  // (16,768,1024)
    const float* msk = (const float*)d_in[2];  // (16,1024,1024)
    const float* U   = (const float*)d_in[3];  // (768,768)
    float* out = (float*)d_out;

    char* ws = (char*)d_ws;
    unsigned char* At = (unsigned char*)ws;                   // 12,582,912
    unsigned char* Bt = (unsigned char*)(ws + 12582912);      // 12,582,912
    unsigned char* Ct = (unsigned char*)(ws + 25165824);      // 12,582,912
    unsigned char* Ut = (unsigned char*)(ws + 37748736);      //    589,824
    unsigned* keyA   = (unsigned*)(ws + 38338560);
    unsigned* keyB   = (unsigned*)(ws + 38404096);
    float*    scoreA = (float*)   (ws + 38469632);
    float*    scoreB = (float*)   (ws + 38535168);

    t_cast_U<<<dim3(DIM / 64, DIM / 64, 1), 256, 0, stream>>>(U, Ut, keyA, keyB);
    t_cast_AB<<<dim3(SEQA / 64, DIM / 64, 2 * BSZ), 256, 0, stream>>>(A, B, At, Bt);
    // k1: R5-measured 128^2 / 3-per-CU structure
    k1_ua<<<dim3(SEQA / 128, DIM / 128, BSZ), 256, 0, stream>>>(At, Ut, Ct);
    // k2: R5-measured 128^2 / 4-per-CU structure + tanh-after-max
    k2_align<<<dim3(SEQB / 128, SEQA / 128, BSZ), 256, 0, stream>>>(Ct, Bt, msk, keyA, keyB);
    k3_softmax<<<dim3(BSZ, 2), 256, 0, stream>>>(keyA, keyB, scoreA, scoreB);
    k4_out<<<dim3(BSZ * DIM / 4, 2), 256, 0, stream>>>(A, B, scoreA, scoreB, out);
}

// Round 19
// 231.568 us; speedup vs baseline: 1.0553x; 1.0319x over previous
//
#include <hip/hip_runtime.h>
#include <math.h>

#define BSZ  16
#define DIM  768
#define SEQA 1024
#define SEQB 1024

typedef float f32x4 __attribute__((ext_vector_type(4)));
typedef long long llong;

__device__ inline void gload_lds16(const void* g, void* l) {
    __builtin_amdgcn_global_load_lds(
        (const __attribute__((address_space(1))) void*)g,
        (__attribute__((address_space(3))) void*)l, 16, 0, 0);
}

// ---- float <-> order-preserving uint key (atomicMax on floats) ----
__device__ inline unsigned enc_key(float f) {
    unsigned u = __float_as_uint(f);
    return (u & 0x80000000u) ? ~u : (u | 0x80000000u);
}
__device__ inline float dec_key(unsigned k) {
    return (k & 0x80000000u) ? __uint_as_float(k ^ 0x80000000u) : __uint_as_float(~k);
}

// ---- fp8 e4m3 (OCP) pack helpers ----
__device__ inline unsigned pk4_fp8(float a, float b, float c, float d) {
    int v = 0;
    v = __builtin_amdgcn_cvt_pk_fp8_f32(a, b, v, false);
    v = __builtin_amdgcn_cvt_pk_fp8_f32(c, d, v, true);
    return (unsigned)v;
}
__device__ inline unsigned char f2fp8(float a) {
    return (unsigned char)(__builtin_amdgcn_cvt_pk_fp8_f32(a, a, 0, false) & 0xFF);
}

// tanh via hardware exp: exact 1.0f in saturation, ~1e-6 error mid-range
__device__ inline float fast_tanh(float x) {
    float ax = fabsf(x);
    float u = __expf(-2.0f * ax);
    float th = __fdividef(1.0f - u, 1.0f + u);
    return copysignf(th, x);
}

// ---- L1: cast A (z<16) + cast U / key-init (z==16), one launch ----
__global__ __launch_bounds__(256) void cast_AU(const float* __restrict__ A,
                                               const float* __restrict__ U,
                                               unsigned char* __restrict__ At,
                                               unsigned char* __restrict__ Ut,
                                               unsigned* __restrict__ keyA,
                                               unsigned* __restrict__ keyB) {
    __shared__ float tl[64 * 68];
    const int z = blockIdx.z;
    const int tid = threadIdx.x;
    if (z < BSZ) {
        // A cast: transposed pitch-65 tile (2-way bank alias both phases)
        const int b = z;
        const int d0 = blockIdx.y * 64;
        const int s0 = blockIdx.x * 64;
        const int rr = tid >> 4, c4 = tid & 15;
        const float* Xb = A + ((size_t)b * DIM + d0) * SEQA + s0;
#pragma unroll
        for (int i = 0; i < 4; i++) {
            int d = i * 16 + rr;
            float4 v = *(const float4*)&Xb[(size_t)d * SEQA + c4 * 4];
            tl[(c4 * 4 + 0) * 65 + d] = v.x;
            tl[(c4 * 4 + 1) * 65 + d] = v.y;
            tl[(c4 * 4 + 2) * 65 + d] = v.z;
            tl[(c4 * 4 + 3) * 65 + d] = v.w;
        }
        __syncthreads();
        unsigned char* Yb = At + ((size_t)b * SEQA + s0) * DIM + d0;
        const int m = tid & 15, sl = tid >> 4;
#pragma unroll
        for (int i = 0; i < 4; i++) {
            int s = sl + 16 * i;
            unsigned v = pk4_fp8(tl[s * 65 + 4 * m + 0], tl[s * 65 + 4 * m + 1],
                                 tl[s * 65 + 4 * m + 2], tl[s * 65 + 4 * m + 3]);
            *(unsigned*)&Yb[(size_t)s * DIM + 4 * m] = v;
        }
    } else {
        // U cast (pitch-68 layout) + key init
        if (blockIdx.x >= 12) return;
        const int d0 = blockIdx.y * 64;
        const int e0 = blockIdx.x * 64;
        const int bid = blockIdx.y * 12 + blockIdx.x;
        if (bid < 64) {
            int i = bid * 256 + tid;
            keyA[i] = 0u;
            keyB[i] = 0u;
        }
        const int rr = tid >> 4, c4 = tid & 15;
#pragma unroll
        for (int i = 0; i < 4; i++) {
            int row = i * 16 + rr;
            float4 v = *(const float4*)&U[(size_t)(d0 + row) * DIM + e0 + c4 * 4];
            *(float4*)&tl[row * 68 + c4 * 4] = v;
        }
        __syncthreads();
        const int m = tid & 15, sl = tid >> 4;
#pragma unroll
        for (int i = 0; i < 4; i++) {
            int e = sl + 16 * i;
            unsigned v = pk4_fp8(tl[(4 * m + 0) * 68 + e], tl[(4 * m + 1) * 68 + e],
                                 tl[(4 * m + 2) * 68 + e], tl[(4 * m + 3) * 68 + e]);
            *(unsigned*)&Ut[(size_t)(e0 + e) * DIM + d0 + 4 * m] = v;
        }
    }
}

// Stage a 128-row x 128-byte tile into LDS with granule-XOR swizzle (4-wave form).
__device__ inline void stage_tile(const unsigned char* __restrict__ src, int row0,
                                  int kbyte0, unsigned char* lds, int wid, int lane) {
    const int r8 = lane >> 3;
    const int g  = lane & 7;
    const int gg = g ^ (r8 & 7);
#pragma unroll
    for (int t = 0; t < 4; ++t) {
        int row = row0 + wid * 32 + t * 8 + r8;
        gload_lds16(src + (size_t)row * DIM + kbyte0 + gg * 16,
                    lds + (wid * 32 + t * 8) * 128 + lane * 16);
    }
}

// Read an 8-byte fp8 fragment with matching XOR un-swizzle.
__device__ inline llong frag_read(const unsigned char* lds, int rowbase, int l15,
                                  int quad, int h) {
    int gg = 2 * h + (quad >> 1);
    int off = (rowbase + l15) * 128 + ((gg ^ (l15 & 7)) << 4) + (quad & 1) * 8;
    return *(const llong*)(lds + off);
}

// ---- L2: k1 GEMM (1-in-5 blocks) interleaved with B cast (4-in-5 blocks) ----
// k1 and castB are independent; co-scheduling them lets castB's pure-BW streaming
// fill k1's latency bubbles (m114 cross-block overlap, across workloads).
__global__ __launch_bounds__(256, 3) void k1_castB(const unsigned char* __restrict__ At,
                                                   const unsigned char* __restrict__ Ut,
                                                   unsigned char* __restrict__ Ct,
                                                   const float* __restrict__ B,
                                                   unsigned char* __restrict__ Bt) {
    __shared__ __align__(16) unsigned char smem[32768];
    const int gbid = blockIdx.x;
    const int tid = threadIdx.x;
    if (gbid % 5 == 0) {
        // ---- k1: Ct[b][s][e] = sum_d At[b][s][d] * Ut[e][d] (128x128, BK=128) ----
        const int kid = gbid / 5;              // 0..767
        const int s0 = (kid & 7) * 128;
        const int e0 = ((kid >> 3) % 6) * 128;
        const int b  = kid / 48;
        unsigned char* As = smem;
        unsigned char* Us = smem + 16384;
        const int lane = tid & 63;
        const int wid = tid >> 6;
        const int wr = wid >> 1, wc = wid & 1;
        const int quad = lane >> 4, l15 = lane & 15;

        const unsigned char* Atb = At + (size_t)b * SEQA * DIM;
        f32x4 acc[4][4] = {};

        for (int d0 = 0; d0 < DIM; d0 += 128) {
            stage_tile(Atb + (size_t)s0 * DIM, 0, d0, As, wid, lane);
            stage_tile(Ut + (size_t)e0 * DIM, 0, d0, Us, wid, lane);
            __syncthreads();
#pragma unroll
            for (int h = 0; h < 4; ++h) {
                llong av[4], bv[4];
#pragma unroll
                for (int i = 0; i < 4; ++i) av[i] = frag_read(As, wr * 64 + 16 * i, l15, quad, h);
#pragma unroll
                for (int j = 0; j < 4; ++j) bv[j] = frag_read(Us, wc * 64 + 16 * j, l15, quad, h);
#pragma unroll
                for (int i = 0; i < 4; ++i)
#pragma unroll
                    for (int j = 0; j < 4; ++j)
                        acc[i][j] = __builtin_amdgcn_mfma_f32_16x16x32_fp8_fp8(av[i], bv[j], acc[i][j], 0, 0, 0);
            }
            __syncthreads();
        }
        unsigned char* Cb = Ct + (size_t)b * SEQA * DIM;
#pragma unroll
        for (int i = 0; i < 4; ++i)
#pragma unroll
            for (int j = 0; j < 4; ++j) {
                int e_g = e0 + wc * 64 + 16 * j + l15;
#pragma unroll
                for (int r = 0; r < 4; ++r) {
                    int s_g = s0 + wr * 64 + 16 * i + quad * 4 + r;
                    Cb[(size_t)s_g * DIM + e_g] = f2fp8(acc[i][j][r]);
                }
            }
    } else {
        // ---- castB: B[b][DIM][SEQ] f32 -> Bt[b][SEQ][DIM] fp8, pitch-65 tile ----
        const int cid = gbid - gbid / 5 - 1;   // 0..3071
        const int s0 = (cid & 15) * 64;
        const int d0 = ((cid >> 4) % 12) * 64;
        const int b  = cid / 192;
        float* tl = (float*)smem;
        const int rr = tid >> 4, c4 = tid & 15;
        const float* Xb = B + ((size_t)b * DIM + d0) * SEQA + s0;
#pragma unroll
        for (int i = 0; i < 4; i++) {
            int d = i * 16 + rr;
            float4 v = *(const float4*)&Xb[(size_t)d * SEQA + c4 * 4];
            tl[(c4 * 4 + 0) * 65 + d] = v.x;
            tl[(c4 * 4 + 1) * 65 + d] = v.y;
            tl[(c4 * 4 + 2) * 65 + d] = v.z;
            tl[(c4 * 4 + 3) * 65 + d] = v.w;
        }
        __syncthreads();
        unsigned char* Yb = Bt + ((size_t)b * SEQA + s0) * DIM + d0;
        const int m = tid & 15, sl = tid >> 4;
#pragma unroll
        for (int i = 0; i < 4; i++) {
            int s = sl + 16 * i;
            unsigned v = pk4_fp8(tl[s * 65 + 4 * m + 0], tl[s * 65 + 4 * m + 1],
                                 tl[s * 65 + 4 * m + 2], tl[s * 65 + 4 * m + 3]);
            *(unsigned*)&Yb[(size_t)s * DIM + 4 * m] = v;
        }
    }
}

// ---- L3 (k2): align^T tile = max-then-tanh(Bt x Ct + msk); fused max -> keys ----
// EXACT R18-measured kernel (46.3us best): 128x128, (256,4), epilogue mask add,
// tanh applied once per reduced key (exact: msk in {0,-inf}, tanh monotone).
__global__ __launch_bounds__(256, 4) void k2_align(const unsigned char* __restrict__ Ct,
                                                   const unsigned char* __restrict__ Bt,
                                                   const float* __restrict__ msk,
                                                   unsigned* __restrict__ keyA,
                                                   unsigned* __restrict__ keyB) {
    __shared__ __align__(16) unsigned char Cs[128 * 128];
    __shared__ __align__(16) unsigned char Bs[128 * 128];
    const int b  = blockIdx.z;
    const int t0 = blockIdx.x * 128;
    const int s0 = blockIdx.y * 128;
    const int tid = threadIdx.x;
    const int lane = tid & 63;
    const int wid = tid >> 6;
    const int wr = wid >> 1, wc = wid & 1;
    const int quad = lane >> 4, l15 = lane & 15;

    f32x4 acc[4][4] = {};

    for (int e0 = 0; e0 < DIM; e0 += 128) {
        stage_tile(Ct + (size_t)(b * SEQA + s0) * DIM, 0, e0, Cs, wid, lane);
        stage_tile(Bt + (size_t)(b * SEQB + t0) * DIM, 0, e0, Bs, wid, lane);
        __syncthreads();
#pragma unroll
        for (int h = 0; h < 4; ++h) {
            llong av[4], bv[4];
#pragma unroll
            for (int i = 0; i < 4; ++i) av[i] = frag_read(Bs, wr * 64 + 16 * i, l15, quad, h);
#pragma unroll
            for (int j = 0; j < 4; ++j) bv[j] = frag_read(Cs, wc * 64 + 16 * j, l15, quad, h);
#pragma unroll
            for (int i = 0; i < 4; ++i)
#pragma unroll
                for (int j = 0; j < 4; ++j)
                    acc[i][j] = __builtin_amdgcn_mfma_f32_16x16x32_fp8_fp8(av[i], bv[j], acc[i][j], 0, 0, 0);
        }
        __syncthreads();
    }

    const float* Mb = msk + (size_t)b * SEQA * SEQB;
#pragma unroll
    for (int j = 0; j < 4; ++j) {
        int s_g = s0 + wc * 64 + 16 * j + l15;
#pragma unroll
        for (int i = 0; i < 4; ++i) {
            int t_g = t0 + wr * 64 + 16 * i + quad * 4;
            float4 mvv = *(const float4*)&Mb[(size_t)s_g * SEQB + t_g];
            acc[i][j][0] += mvv.x;
            acc[i][j][1] += mvv.y;
            acc[i][j][2] += mvv.z;
            acc[i][j][3] += mvv.w;
        }
    }
#pragma unroll
    for (int j = 0; j < 4; ++j) {
        float m = -INFINITY;
#pragma unroll
        for (int i = 0; i < 4; ++i)
#pragma unroll
            for (int r = 0; r < 4; ++r) m = fmaxf(m, acc[i][j][r]);
        m = fmaxf(m, __shfl_xor(m, 16));
        m = fmaxf(m, __shfl_xor(m, 32));
        if (quad == 0) {
            float kv = (m == -INFINITY) ? m : fast_tanh(m);
            atomicMax(&keyA[b * SEQA + s0 + wc * 64 + 16 * j + l15], enc_key(kv));
        }
    }
#pragma unroll
    for (int i = 0; i < 4; ++i)
#pragma unroll
        for (int r = 0; r < 4; ++r) {
            float m = fmaxf(fmaxf(acc[i][0][r], acc[i][1][r]), fmaxf(acc[i][2][r], acc[i][3][r]));
            m = fmaxf(m, __shfl_xor(m, 1));
            m = fmaxf(m, __shfl_xor(m, 2));
            m = fmaxf(m, __shfl_xor(m, 4));
            m = fmaxf(m, __shfl_xor(m, 8));
            if (l15 == 0) {
                float kv = (m == -INFINITY) ? m : fast_tanh(m);
                atomicMax(&keyB[b * SEQB + t0 + wr * 64 + 16 * i + quad * 4 + r], enc_key(kv));
            }
        }
}

// ---- L4: k4 with in-block softmax (k3 fused). Each block: softmax over the 1024
// keys of its (which,b) into LDS (~2us aggregate over all blocks), then the dot. ----
__global__ __launch_bounds__(256) void k4s(const float* __restrict__ A,
                                           const float* __restrict__ B,
                                           const unsigned* __restrict__ keyA,
                                           const unsigned* __restrict__ keyB,
                                           float* __restrict__ out) {
    __shared__ __align__(16) float sc[1024];
    __shared__ float red[4];
    const int which = blockIdx.y;
    const int tid = threadIdx.x;
    const int lane = tid & 63;
    const int row = blockIdx.x * 4 + (tid >> 6);
    const int b = (blockIdx.x * 4) / DIM;

    const unsigned* keys = which ? (keyB + b * SEQB) : (keyA + b * SEQA);
    float m[4];
    float mx = -INFINITY;
#pragma unroll
    for (int k = 0; k < 4; k++) {
        m[k] = dec_key(keys[tid + 256 * k]);
        mx = fmaxf(mx, m[k]);
    }
#pragma unroll
    for (int o = 32; o > 0; o >>= 1) mx = fmaxf(mx, __shfl_down(mx, o, 64));
    if (lane == 0) red[tid >> 6] = mx;
    __syncthreads();
    mx = fmaxf(fmaxf(red[0], red[1]), fmaxf(red[2], red[3]));
    __syncthreads();
    float e4[4];
    float sum = 0.f;
#pragma unroll
    for (int k = 0; k < 4; k++) { e4[k] = expf(m[k] - mx); sum += e4[k]; }
#pragma unroll
    for (int o = 32; o > 0; o >>= 1) sum += __shfl_down(sum, o, 64);
    if (lane == 0) red[tid >> 6] = sum;
    __syncthreads();
    sum = red[0] + red[1] + red[2] + red[3];
    float inv = 1.0f / sum;
#pragma unroll
    for (int k = 0; k < 4; k++) sc[tid + 256 * k] = e4[k] * inv;
    __syncthreads();

    const float* X = which ? B : A;
    const float4* xr = (const float4*)(X + (size_t)row * SEQA);
    float acc = 0.f;
#pragma unroll
    for (int q = lane; q < SEQA / 4; q += 64) {
        float4 x = xr[q];
        float4 s = *(const float4*)&sc[q * 4];
        acc += x.x * s.x + x.y * s.y + x.z * s.z + x.w * s.w;
    }
#pragma unroll
    for (int o = 32; o > 0; o >>= 1) acc += __shfl_down(acc, o, 64);
    if (lane == 0) out[which * (BSZ * DIM) + row] = acc;
}

extern "C" void kernel_launch(void* const* d_in, const int* in_sizes, int n_in,
                              void* d_out, int out_size, void* d_ws, size_t ws_size,
                              hipStream_t stream) {
    const float* A   = (const float*)d_in[0];  // (16,768,1024)
    const float* B   = (const float*)d_in[1];  // (16,768,1024)
    const float* msk = (const float*)d_in[2];  // (16,1024,1024)
    const float* U   = (const float*)d_in[3];  // (768,768)
    float* out = (float*)d_out;

    char* ws = (char*)d_ws;
    unsigned char* At = (unsigned char*)ws;                   // 12,582,912
    unsigned char* Bt = (unsigned char*)(ws + 12582912);      // 12,582,912
    unsigned char* Ct = (unsigned char*)(ws + 25165824);      // 12,582,912
    unsigned char* Ut = (unsigned char*)(ws + 37748736);      //    589,824
    unsigned* keyA   = (unsigned*)(ws + 38338560);
    unsigned* keyB   = (unsigned*)(ws + 38404096);

    // L1: A cast + U cast + key init (z==16 slice does U; x>=12 blocks idle there)
    cast_AU<<<dim3(SEQA / 64, DIM / 64, BSZ + 1), 256, 0, stream>>>(A, U, At, Ut, keyA, keyB);
    // L2: k1 (768 blocks, 1-in-5) interleaved with B cast (3072 blocks)
    k1_castB<<<dim3(3840, 1, 1), 256, 0, stream>>>(At, Ut, Ct, B, Bt);
    // L3: k2 (R18-measured best)
    k2_align<<<dim3(SEQB / 128, SEQA / 128, BSZ), 256, 0, stream>>>(Ct, Bt, msk, keyA, keyB);
    // L4: k4 with fused softmax
    k4s<<<dim3(BSZ * DIM / 4, 2), 256, 0, stream>>>(A, B, keyA, keyB, out);
}